// Round 1
// baseline (1169.383 us; speedup 1.0000x reference)
//
#include <hip/hip_runtime.h>
#include <stdint.h>

#define DEVI __device__ __forceinline__

typedef __attribute__((ext_vector_type(8))) short short8;
typedef __attribute__((ext_vector_type(4))) float f32x4;
typedef unsigned short u16;
typedef unsigned int u32;

typedef const __attribute__((address_space(1))) void* gas_ptr;
typedef __attribute__((address_space(3))) void* las_ptr;

constexpr int BBATCH = 2;
constexpr int TT  = 1024;
constexpr int BT  = BBATCH * TT;   // 2048 tokens
constexpr int DM  = 1024;
constexpr int NH  = 16;
constexpr int HD  = 64;
constexpr int DFF = 4096;
constexpr int NV  = 32000;
constexpr int NL  = 4;

DEVI u16 f2b(float f) {
  u32 u = __builtin_bit_cast(u32, f);
  u = (u + 0x7fffu + ((u >> 16) & 1u)) >> 16;
  return (u16)u;
}
DEVI float b2f(u16 h) { return __builtin_bit_cast(float, (u32)h << 16); }

DEVI void gld16(const void* g, void* l) {
  __builtin_amdgcn_global_load_lds((gas_ptr)g, (las_ptr)l, 16, 0, 0);
}

DEVI float wave_sum(float v) {
#pragma unroll
  for (int off = 32; off; off >>= 1) v += __shfl_xor(v, off);
  return v;
}
DEVI float wave_max(float v) {
#pragma unroll
  for (int off = 32; off; off >>= 1) v = fmaxf(v, __shfl_xor(v, off));
  return v;
}
// 256-thread (4-wave) block reductions; leading barrier makes sb reusable.
DEVI float block_sum(float v, float* sb) {
  v = wave_sum(v);
  int lane = threadIdx.x & 63, wid = threadIdx.x >> 6;
  __syncthreads();
  if (lane == 0) sb[wid] = v;
  __syncthreads();
  return sb[0] + sb[1] + sb[2] + sb[3];
}
DEVI float block_max(float v, float* sb) {
  v = wave_max(v);
  int lane = threadIdx.x & 63, wid = threadIdx.x >> 6;
  __syncthreads();
  if (lane == 0) sb[wid] = v;
  __syncthreads();
  return fmaxf(fmaxf(sb[0], sb[1]), fmaxf(sb[2], sb[3]));
}

DEVI float gelu_f(float x) {
  float u = 0.7978845608028654f * (x + 0.044715f * x * x * x);
  float e = __expf(2.0f * u);            // gelu = x * sigmoid(2u)
  return x * (1.0f - 1.0f / (e + 1.0f));
}

// ---------------- weight transpose+convert: f32 [K][N] -> bf16 [N][K] ----------------
__global__ __launch_bounds__(256) void wt_transpose(const float* __restrict__ in,
                                                    u16* __restrict__ out, int K, int N) {
  __shared__ float t[32][33];
  int n0 = blockIdx.x * 32, k0 = blockIdx.y * 32;
  int tx = threadIdx.x, ty = threadIdx.y;
#pragma unroll
  for (int i = 0; i < 4; ++i)
    t[ty + 8 * i][tx] = in[(size_t)(k0 + ty + 8 * i) * N + n0 + tx];
  __syncthreads();
#pragma unroll
  for (int i = 0; i < 4; ++i)
    out[(size_t)(n0 + ty + 8 * i) * K + k0 + tx] = f2b(t[tx][ty + 8 * i]);
}

// ---------------- V transpose: qkv bf16 [b*T][3D] (v slice) -> vT [bh][64][1024] ----------------
__global__ __launch_bounds__(256) void v_transpose(const u16* __restrict__ qkv,
                                                   u16* __restrict__ vT) {
  __shared__ u16 t[32][33];
  int bh = blockIdx.z, b = bh >> 4, h = bh & 15;
  int d0 = blockIdx.x * 32, t0 = blockIdx.y * 32;
  int tx = threadIdx.x, ty = threadIdx.y;
  const u16* src = qkv + (size_t)b * TT * 3 * DM + 2 * DM + h * HD;
#pragma unroll
  for (int i = 0; i < 4; ++i)
    t[ty + 8 * i][tx] = src[(size_t)(t0 + ty + 8 * i) * (3 * DM) + d0 + tx];
  __syncthreads();
  u16* dst = vT + (size_t)bh * HD * TT;
#pragma unroll
  for (int i = 0; i < 4; ++i)
    dst[(size_t)(d0 + ty + 8 * i) * TT + t0 + tx] = t[tx][ty + 8 * i];
}

// ---------------- embedding gather + LayerNorm -> x f32 ----------------
__global__ __launch_bounds__(256) void embed_ln_k(const int* __restrict__ idx,
                                                  const float* __restrict__ tok,
                                                  const float* __restrict__ g,
                                                  const float* __restrict__ b,
                                                  float* __restrict__ x) {
  __shared__ float sb[4];
  int row = blockIdx.x, tid = threadIdx.x;
  float4 v = ((const float4*)(tok + (size_t)idx[row] * DM))[tid];
  float s = block_sum(v.x + v.y + v.z + v.w, sb);
  float m = s * (1.0f / DM);
  float dx = v.x - m, dy = v.y - m, dz = v.z - m, dw = v.w - m;
  float q = block_sum(dx * dx + dy * dy + dz * dz + dw * dw, sb);
  float rs = rsqrtf(q * (1.0f / DM) + 1e-5f);
  float4 gg = ((const float4*)g)[tid];
  float4 bb = ((const float4*)b)[tid];
  float4 o = make_float4(dx * rs * gg.x + bb.x, dy * rs * gg.y + bb.y,
                         dz * rs * gg.z + bb.z, dw * rs * gg.w + bb.w);
  ((float4*)(x + (size_t)row * DM))[tid] = o;
}

// ---------------- final LayerNorm -> bf16 ----------------
__global__ __launch_bounds__(256) void final_ln_k(const float* __restrict__ x,
                                                  const float* __restrict__ g,
                                                  const float* __restrict__ b,
                                                  u16* __restrict__ xf) {
  __shared__ float sb[4];
  int row = blockIdx.x, tid = threadIdx.x;
  float4 v = ((const float4*)(x + (size_t)row * DM))[tid];
  float s = block_sum(v.x + v.y + v.z + v.w, sb);
  float m = s * (1.0f / DM);
  float dx = v.x - m, dy = v.y - m, dz = v.z - m, dw = v.w - m;
  float q = block_sum(dx * dx + dy * dy + dz * dz + dw * dw, sb);
  float rs = rsqrtf(q * (1.0f / DM) + 1e-5f);
  float4 gg = ((const float4*)g)[tid];
  float4 bb = ((const float4*)b)[tid];
  u32 lo = (u32)f2b(dx * rs * gg.x + bb.x) | ((u32)f2b(dy * rs * gg.y + bb.y) << 16);
  u32 hi = (u32)f2b(dz * rs * gg.z + bb.z) | ((u32)f2b(dw * rs * gg.w + bb.w) << 16);
  ((uint2*)(xf + (size_t)row * DM))[tid] = make_uint2(lo, hi);
}

// ---------------- RMSNorm f32 -> bf16 ----------------
__global__ __launch_bounds__(256) void rmsnorm_k(const float* __restrict__ x,
                                                 const float* __restrict__ w,
                                                 u16* __restrict__ h) {
  __shared__ float sb[4];
  int row = blockIdx.x, tid = threadIdx.x;
  float4 v = ((const float4*)(x + (size_t)row * DM))[tid];
  float q = block_sum(v.x * v.x + v.y * v.y + v.z * v.z + v.w * v.w, sb);
  float rs = rsqrtf(q * (1.0f / DM) + 1.1920928955078125e-7f);
  float4 ww = ((const float4*)w)[tid];
  u32 lo = (u32)f2b(v.x * rs * ww.x) | ((u32)f2b(v.y * rs * ww.y) << 16);
  u32 hi = (u32)f2b(v.z * rs * ww.z) | ((u32)f2b(v.w * rs * ww.w) << 16);
  ((uint2*)(h + (size_t)row * DM))[tid] = make_uint2(lo, hi);
}

// ---------------- row softmax, in place on bf16 S rows of length 1024 ----------------
__global__ __launch_bounds__(256) void softmax_k(u16* __restrict__ S) {
  __shared__ float sb[4];
  size_t row = blockIdx.x;
  u16* p = S + row * TT;
  int tid = threadIdx.x;
  uint2 d = ((const uint2*)p)[tid];
  float v0 = b2f((u16)(d.x & 0xffff)), v1 = b2f((u16)(d.x >> 16));
  float v2 = b2f((u16)(d.y & 0xffff)), v3 = b2f((u16)(d.y >> 16));
  float m = block_max(fmaxf(fmaxf(v0, v1), fmaxf(v2, v3)), sb);
  float e0 = __expf(v0 - m), e1 = __expf(v1 - m), e2 = __expf(v2 - m), e3 = __expf(v3 - m);
  float s = block_sum(e0 + e1 + e2 + e3, sb);
  float inv = 1.0f / s;
  u32 lo = (u32)f2b(e0 * inv) | ((u32)f2b(e1 * inv) << 16);
  u32 hi = (u32)f2b(e2 * inv) | ((u32)f2b(e3 * inv) << 16);
  ((uint2*)p)[tid] = make_uint2(lo, hi);
}

// ---------------- GEMM: C = A[M][K](bf16,k-major) * Bt[N][K](bf16,k-major)^T + bias ----------------
enum { EPI_BF16 = 0, EPI_GELU = 1, EPI_ADDF32 = 2, EPI_F32 = 3, EPI_QK = 4 };

template <int BM, int BN, int WM, int WN, int EPI>
__global__ __launch_bounds__(256, 2) void gemm_bt(
    const u16* __restrict__ A, int lda, const u16* __restrict__ Bt, int ldb,
    const float* __restrict__ bias, void* __restrict__ C, int ldc,
    float* __restrict__ resid, int K, int causalTrim,
    int aDiv, long long aOuter, int aInner,
    int bDiv, long long bOuter, int bInner,
    int cDiv, long long cOuter, int cInner) {
  constexpr int BK = 64;                       // 128 bytes per LDS row
  constexpr int NW = WM * WN;                  // 4 waves
  constexpr int FM = BM / WM / 16, FN = BN / WN / 16;
  constexpr int ABYTES = BM * BK * 2, BBYTES = BN * BK * 2;
  constexpr int ACH = ABYTES / 1024, BCH = BBYTES / 1024, NCH = ACH + BCH;
  extern __shared__ __align__(16) char smem[];

  const int tid = threadIdx.x, lane = tid & 63, wid = tid >> 6;
  const int brow = blockIdx.y * BM, bcol = blockIdx.x * BN;
  const int batch = blockIdx.z;

  const long long cOff = (long long)(batch / cDiv) * cOuter + (long long)(batch % cDiv) * cInner;

  if constexpr (EPI == EPI_QK) {
    // fully-masked tile (all cols > all rows): write -1e30 and exit
    if (bcol > brow + (BM - 1)) {
      u16* Sb = (u16*)C + cOff;
      u16 neg = f2b(-1e30f);
      for (int i = tid; i < BM * BN; i += 256)
        Sb[(size_t)(brow + (i >> 7)) * ldc + bcol + (i & 127)] = neg;
      return;
    }
  }

  const u16* Ab = A + (long long)(batch / aDiv) * aOuter + (long long)(batch % aDiv) * aInner;
  const u16* Bb = Bt + (long long)(batch / bDiv) * bOuter + (long long)(batch % bDiv) * bInner;

  int nt = K >> 6;
  if (causalTrim) { int mx = (blockIdx.y + 1) * (BM / BK); nt = nt < mx ? nt : mx; }

  const int widm = wid / WN, widn = wid % WN;
  const int rm0 = widm * (BM / WM), cn0 = widn * (BN / WN);

  f32x4 acc[FM][FN] = {};

  // T2 swizzle (both sides): LDS[row][cq] holds global[row][cq ^ (row&7)] (16B quads)
  const int swq16 = (((lane & 7) ^ ((lane >> 3) & 7)) << 4);  // inverse-swizzled source quad
  const int lrow8 = lane >> 3;

  auto stage = [&](int buf, int kt) {
    char* base = smem + buf * (ABYTES + BBYTES);
    const char* Ag = (const char*)Ab;
    const char* Bg = (const char*)Bb;
    long long kOff = (long long)kt * 128 + swq16;
#pragma unroll
    for (int ci = 0; ci < NCH / NW; ++ci) {
      int c = wid + ci * NW;
      if (c < ACH) {
        int r = c * 8 + lrow8;
        gld16(Ag + (long long)(brow + r) * (lda * 2) + kOff, base + c * 1024 + lane * 16);
      } else {
        int r = (c - ACH) * 8 + lrow8;
        gld16(Bg + (long long)(bcol + r) * (ldb * 2) + kOff,
              base + ABYTES + (c - ACH) * 1024 + lane * 16);
      }
    }
  };

  auto compute = [&](int buf) {
    char* baseA = smem + buf * (ABYTES + BBYTES);
    char* baseB = baseA + ABYTES;
#pragma unroll
    for (int ks = 0; ks < 2; ++ks) {
      short8 af[FM], bv[FN];
#pragma unroll
      for (int i = 0; i < FM; ++i) {
        int r = rm0 + i * 16 + (lane & 15);
        int cq = ((ks << 2) + (lane >> 4)) ^ (r & 7);
        af[i] = *(const short8*)(baseA + r * 128 + (cq << 4));
      }
#pragma unroll
      for (int j = 0; j < FN; ++j) {
        int r = cn0 + j * 16 + (lane & 15);
        int cq = ((ks << 2) + (lane >> 4)) ^ (r & 7);
        bv[j] = *(const short8*)(baseB + r * 128 + (cq << 4));
      }
#pragma unroll
      for (int i = 0; i < FM; ++i)
#pragma unroll
        for (int j = 0; j < FN; ++j)
          acc[i][j] = __builtin_amdgcn_mfma_f32_16x16x32_bf16(af[i], bv[j], acc[i][j], 0, 0, 0);
    }
  };

  // minimum 2-phase pipeline: issue next-tile stage, compute current, barrier drains
  stage(0, 0);
  __syncthreads();
  int cur = 0;
  for (int t = 0; t < nt; ++t) {
    if (t + 1 < nt) stage(cur ^ 1, t + 1);
    compute(cur);
    __syncthreads();
    cur ^= 1;
  }

  // epilogue: D row=(lane>>4)*4+reg, col=lane&15 (measured layout)
  const int r0 = brow + rm0 + ((lane >> 4) << 2);
  const int c0 = bcol + cn0 + (lane & 15);
#pragma unroll
  for (int i = 0; i < FM; ++i) {
#pragma unroll
    for (int j = 0; j < FN; ++j) {
#pragma unroll
      for (int r = 0; r < 4; ++r) {
        int row = r0 + i * 16 + r;
        int col = c0 + j * 16;
        float v = acc[i][j][r];
        if constexpr (EPI == EPI_QK) {
          int hh = batch & 15;
          float slope = exp2f(-0.5f * (hh + 1));
          float val = (col <= row) ? (v * 0.125f - slope * (float)(row - col)) : -1e30f;
          ((u16*)C + cOff)[(size_t)row * ldc + col] = f2b(val);
        } else if constexpr (EPI == EPI_BF16) {
          float val = v + (bias ? bias[col] : 0.0f);
          ((u16*)C + cOff)[(size_t)row * ldc + col] = f2b(val);
        } else if constexpr (EPI == EPI_GELU) {
          ((u16*)C)[(size_t)row * ldc + col] = f2b(gelu_f(v + bias[col]));
        } else if constexpr (EPI == EPI_ADDF32) {
          size_t o = (size_t)row * ldc + col;
          resid[o] += v + bias[col];
        } else {  // EPI_F32
          ((float*)C)[(size_t)row * ldc + col] = v + bias[col];
        }
      }
    }
  }
}

extern "C" void kernel_launch(void* const* d_in, const int* in_sizes, int n_in,
                              void* d_out, int out_size, void* d_ws, size_t ws_size,
                              hipStream_t stream) {
  (void)in_sizes; (void)n_in; (void)out_size;
  const int*   idx    = (const int*)d_in[0];
  const float* tok    = (const float*)d_in[1];
  const float* ln_e_g = (const float*)d_in[2];
  const float* ln_e_b = (const float*)d_in[3];
  const float* Wqkv   = (const float*)d_in[4];
  const float* bqkv   = (const float*)d_in[5];
  const float* Wo     = (const float*)d_in[6];
  const float* bo     = (const float*)d_in[7];
  const float* W1     = (const float*)d_in[8];
  const float* b1     = (const float*)d_in[9];
  const float* W2     = (const float*)d_in[10];
  const float* b2     = (const float*)d_in[11];
  const float* n1_w   = (const float*)d_in[12];
  const float* n2_w   = (const float*)d_in[13];
  const float* lnf_g  = (const float*)d_in[14];
  const float* lnf_b  = (const float*)d_in[15];
  const float* Wlm    = (const float*)d_in[16];
  const float* blm    = (const float*)d_in[17];
  float* out = (float*)d_out;

  char* w = (char*)d_ws;
  auto alloc = [&](size_t bytes) { char* p = w; w += (bytes + 255) & ~(size_t)255; return p; };
  float* x   = (float*)alloc((size_t)BT * DM * 4);
  u16* h     = (u16*)alloc((size_t)BT * DM * 2);
  u16* qkv   = (u16*)alloc((size_t)BT * 3 * DM * 2);
  u16* vT    = (u16*)alloc((size_t)BBATCH * NH * HD * TT * 2);
  u16* S     = (u16*)alloc((size_t)BBATCH * NH * TT * TT * 2);
  u16* y     = (u16*)alloc((size_t)BT * DM * 2);
  u16* act   = (u16*)alloc((size_t)BT * DFF * 2);
  u16* xf    = (u16*)alloc((size_t)BT * DM * 2);
  u16* WqkvT = (u16*)alloc((size_t)3 * DM * DM * 2);
  u16* WoT   = (u16*)alloc((size_t)DM * DM * 2);
  u16* W1T   = (u16*)alloc((size_t)DFF * DM * 2);
  u16* W2T   = (u16*)alloc((size_t)DM * DFF * 2);
  u16* WlmT  = (u16*)alloc((size_t)NV * DM * 2);
  if ((size_t)(w - (char*)d_ws) > ws_size) return;  // ws too small -> visible failure

  dim3 t328(32, 8);
  wt_transpose<<<dim3(3 * DM / 32, DM / 32), t328, 0, stream>>>(Wqkv, WqkvT, DM, 3 * DM);
  wt_transpose<<<dim3(DM / 32, DM / 32), t328, 0, stream>>>(Wo, WoT, DM, DM);
  wt_transpose<<<dim3(DFF / 32, DM / 32), t328, 0, stream>>>(W1, W1T, DM, DFF);
  wt_transpose<<<dim3(DM / 32, DFF / 32), t328, 0, stream>>>(W2, W2T, DFF, DM);
  wt_transpose<<<dim3(NV / 32, DM / 32), t328, 0, stream>>>(Wlm, WlmT, DM, NV);

  embed_ln_k<<<BT, 256, 0, stream>>>(idx, tok, ln_e_g, ln_e_b, x);

  constexpr int SM128 = 2 * (128 * 64 * 2 + 128 * 64 * 2);  // 65536
  constexpr int SMPV  = 2 * (128 * 64 * 2 + 64 * 64 * 2);   // 49152

  for (int l = 0; l < NL; ++l) {
    rmsnorm_k<<<BT, 256, 0, stream>>>(x, n1_w, h);
    gemm_bt<128, 128, 2, 2, EPI_BF16><<<dim3(3 * DM / 128, BT / 128, 1), 256, SM128, stream>>>(
        h, DM, WqkvT, DM, bqkv, qkv, 3 * DM, nullptr, DM, 0,
        1, 0, 0, 1, 0, 0, 1, 0, 0);
    v_transpose<<<dim3(HD / 32, TT / 32, BBATCH * NH), t328, 0, stream>>>(qkv, vT);
    gemm_bt<128, 128, 2, 2, EPI_QK><<<dim3(TT / 128, TT / 128, BBATCH * NH), 256, SM128, stream>>>(
        qkv, 3 * DM, qkv + DM, 3 * DM, nullptr, S, TT, nullptr, HD, 0,
        NH, (long long)TT * 3 * DM, HD,
        NH, (long long)TT * 3 * DM, HD,
        1, (long long)TT * TT, 0);
    softmax_k<<<BBATCH * NH * TT, 256, 0, stream>>>(S);
    gemm_bt<128, 64, 4, 1, EPI_BF16><<<dim3(1, TT / 128, BBATCH * NH), 256, SMPV, stream>>>(
        S, TT, vT, TT, nullptr, y, DM, nullptr, TT, 1,
        1, (long long)TT * TT, 0,
        1, (long long)HD * TT, 0,
        NH, (long long)TT * DM, HD);
    gemm_bt<128, 128, 2, 2, EPI_ADDF32><<<dim3(DM / 128, BT / 128, 1), 256, SM128, stream>>>(
        y, DM, WoT, DM, bo, nullptr, DM, x, DM, 0,
        1, 0, 0, 1, 0, 0, 1, 0, 0);
    rmsnorm_k<<<BT, 256, 0, stream>>>(x, n2_w, h);
    gemm_bt<128, 128, 2, 2, EPI_GELU><<<dim3(DFF / 128, BT / 128, 1), 256, SM128, stream>>>(
        h, DM, W1T, DM, b1, act, DFF, nullptr, DM, 0,
        1, 0, 0, 1, 0, 0, 1, 0, 0);
    gemm_bt<128, 128, 2, 2, EPI_ADDF32><<<dim3(DM / 128, BT / 128, 1), 256, SM128, stream>>>(
        act, DFF, W2T, DFF, b2, nullptr, DM, x, DFF, 0,
        1, 0, 0, 1, 0, 0, 1, 0, 0);
  }

  final_ln_k<<<BT, 256, 0, stream>>>(x, lnf_g, lnf_b, xf);
  gemm_bt<128, 128, 2, 2, EPI_F32><<<dim3(NV / 128, BT / 128, 1), 256, SM128, stream>>>(
      xf, DM, WlmT, DM, blm, out, NV, nullptr, DM, 0,
      1, 0, 0, 1, 0, 0, 1, 0, 0);
}